// Round 2
// baseline (549.721 us; speedup 1.0000x reference)
//
#include <hip/hip_runtime.h>
#include <math.h>

// Problem constants (B=8, C=192, H=W=32)
#define BB 8
#define CC 192
#define LL 1024
#define RT 8192         // total rows = BB*LL
#define DI 384          // d_inner
#define DT_RANK 12
#define NS 16           // D_STATE
#define NSEG 16
#define SEGL 64

// ---------------------------------------------------------------------------
// DPP butterfly sum across a row of 16 lanes (lanes 16k..16k+15).
__device__ __forceinline__ float row_sum16(float v) {
    v += __int_as_float(__builtin_amdgcn_update_dpp(0, __float_as_int(v), 0x140, 0xF, 0xF, true));
    v += __int_as_float(__builtin_amdgcn_update_dpp(0, __float_as_int(v), 0x141, 0xF, 0xF, true));
    v += __int_as_float(__builtin_amdgcn_update_dpp(0, __float_as_int(v), 0x4E,  0xF, 0xF, true));
    v += __int_as_float(__builtin_amdgcn_update_dpp(0, __float_as_int(v), 0xB1,  0xF, 0xF, true));
    return v;
}

// ---------------------------------------------------------------------------
// K1: W2[j,c'] = sum_c in_proj_w[j,c]*proj_w[c,c'];  bias2[j] = in_proj_w[j,:]·proj_b
// Also zeroes the scan flag array + ticket (workspace is poisoned each iter).
__global__ void fuse_w_kernel(const float* __restrict__ in_proj_w,
                              const float* __restrict__ proj_w,
                              const float* __restrict__ proj_b,
                              float* __restrict__ W2, float* __restrict__ bias2,
                              int* __restrict__ flags, int* __restrict__ ticket) {
    int j = blockIdx.x;
    int cp = threadIdx.x;
    if (cp < 4) flags[j * 4 + cp] = 0;           // 768*4 = 3072 flags
    if (j == 0 && cp == 4) *ticket = 0;
    __shared__ float wrow[CC];
    wrow[cp] = in_proj_w[j * CC + cp];
    __syncthreads();
    float acc = 0.f;
#pragma unroll 4
    for (int c = 0; c < CC; ++c) acc = fmaf(wrow[c], proj_w[c * CC + cp], acc);
    W2[j * CC + cp] = acc;
    if (cp == 0) {
        float b = 0.f;
        for (int c = 0; c < CC; ++c) b = fmaf(wrow[c], proj_b[c], b);
        bias2[j] = b;
    }
}

// ---------------------------------------------------------------------------
// K2: xzT[j, row] = sum_c x[b, c, l] * W2[j, c] + bias2[j]   (row = b*1024+l)
__global__ __launch_bounds__(256) void gemm_xz(const float* __restrict__ x,
                                               const float* __restrict__ W2,
                                               const float* __restrict__ bias2,
                                               float* __restrict__ xzT) {
    __shared__ float As[16][132];  // [k][row]
    __shared__ float Bs[16][100];  // [k][j]
    int r0 = blockIdx.x * 128;
    int j0 = blockIdx.y * 96;
    int b  = r0 >> 10;
    int l0 = r0 & 1023;
    int tid = threadIdx.x;
    int tx = tid & 15;   // row quad (x2, split 64 apart)
    int ty = tid >> 4;   // j sextet
    float acc[6][8] = {};
    const float* xb = x + b * CC * LL;
    for (int k0 = 0; k0 < CC; k0 += 16) {
#pragma unroll
        for (int it = 0; it < 2; ++it) {     // A: 16k x 128row = 512 float4
            int idx = tid + it * 256;
            int k = idx >> 5, l4 = (idx & 31) * 4;
            *(float4*)&As[k][l4] = *(const float4*)&xb[(k0 + k) * LL + l0 + l4];
        }
#pragma unroll
        for (int it = 0; it < 2; ++it) {     // B: 96j x 16k = 384 float4
            int idx = tid + it * 256;
            if (idx < 384) {
                int j = idx >> 2, kq = (idx & 3) * 4;
                float4 v = *(const float4*)&W2[(j0 + j) * CC + k0 + kq];
                Bs[kq + 0][j] = v.x; Bs[kq + 1][j] = v.y;
                Bs[kq + 2][j] = v.z; Bs[kq + 3][j] = v.w;
            }
        }
        __syncthreads();
#pragma unroll
        for (int k = 0; k < 16; ++k) {
            float4 a0 = *(const float4*)&As[k][tx * 4];
            float4 a1 = *(const float4*)&As[k][64 + tx * 4];
            float ar[8] = {a0.x, a0.y, a0.z, a0.w, a1.x, a1.y, a1.z, a1.w};
            float br[6];
#pragma unroll
            for (int q = 0; q < 6; ++q) br[q] = Bs[k][ty * 6 + q];
#pragma unroll
            for (int jc = 0; jc < 6; ++jc)
#pragma unroll
                for (int rc = 0; rc < 8; ++rc)
                    acc[jc][rc] = fmaf(br[jc], ar[rc], acc[jc][rc]);
        }
        __syncthreads();
    }
    bool is_z = (j0 >= DI);
#pragma unroll
    for (int jc = 0; jc < 6; ++jc) {
        int j = j0 + ty * 6 + jc;
        float bval = bias2[j];
        float o[8];
#pragma unroll
        for (int rc = 0; rc < 8; ++rc) o[rc] = acc[jc][rc] + bval;
        if (is_z) {
#pragma unroll
            for (int rc = 0; rc < 8; ++rc)
                o[rc] = __fdividef(o[rc], 1.f + __expf(-o[rc]));
        }
        float4 o0 = make_float4(o[0], o[1], o[2], o[3]);
        float4 o1 = make_float4(o[4], o[5], o[6], o[7]);
        *(float4*)&xzT[j * RT + r0 + tx * 4]      = o0;
        *(float4*)&xzT[j * RT + r0 + 64 + tx * 4] = o1;
    }
}

// ---------------------------------------------------------------------------
// K3: skinny GEMM with fused causal depthwise conv (k=4) + silu in staging.
__global__ __launch_bounds__(512) void xproj_conv_gemm(const float* __restrict__ xzT,
                                                       const float* __restrict__ conv_w,
                                                       const float* __restrict__ conv_b,
                                                       const float* __restrict__ aw,
                                                       float* __restrict__ xcT,
                                                       float* __restrict__ xdT) {
    __shared__ float Bs[32][64];
    int col0 = blockIdx.x * 64;
    int tid = threadIdx.x;
    int col = tid & 63, mg = tid >> 6;          // mg wave-uniform -> scalar A loads
    int mb = blockIdx.y * 24 + mg * 3;
    const float* a0 = aw + min(mb + 0, 43) * DI;
    const float* a1 = aw + min(mb + 1, 43) * DI;
    const float* a2 = aw + min(mb + 2, 43) * DI;
    float acc0 = 0.f, acc1 = 0.f, acc2 = 0.f;
    int ks = tid >> 4, c4 = (tid & 15) * 4;
    bool atL0 = ((col0 & 1023) == 0) && (c4 == 0);   // conv zero-pad boundary
    bool wr = (blockIdx.y == 0);
    for (int k0 = 0; k0 < DI; k0 += 32) {
        int dch = k0 + ks;
        const float* src = xzT + (size_t)dch * RT + col0 + c4;
        float4 cur = *(const float4*)src;
        float4 prev = make_float4(0.f, 0.f, 0.f, 0.f);
        if (!atL0) prev = *(const float4*)(src - 4);
        float4 w4 = *(const float4*)&conv_w[dch * 4];   // w0=x w1=y w2=z w3=w
        float bb = conv_b[dch];
        float v0 = bb + w4.w * cur.x + w4.z * prev.w + w4.y * prev.z + w4.x * prev.y;
        float v1 = bb + w4.w * cur.y + w4.z * cur.x  + w4.y * prev.w + w4.x * prev.z;
        float v2 = bb + w4.w * cur.z + w4.z * cur.y  + w4.y * cur.x  + w4.x * prev.w;
        float v3 = bb + w4.w * cur.w + w4.z * cur.z  + w4.y * cur.y  + w4.x * cur.x;
        float4 o;
        o.x = __fdividef(v0, 1.f + __expf(-v0));
        o.y = __fdividef(v1, 1.f + __expf(-v1));
        o.z = __fdividef(v2, 1.f + __expf(-v2));
        o.w = __fdividef(v3, 1.f + __expf(-v3));
        *(float4*)&Bs[ks][c4] = o;
        if (wr) *(float4*)&xcT[(size_t)dch * RT + col0 + c4] = o;
        __syncthreads();
#pragma unroll
        for (int k = 0; k < 32; ++k) {
            float bv = Bs[k][col];
            acc0 = fmaf(a0[k0 + k], bv, acc0);
            acc1 = fmaf(a1[k0 + k], bv, acc1);
            acc2 = fmaf(a2[k0 + k], bv, acc2);
        }
        __syncthreads();
    }
    if (mb + 0 < 44) xdT[(mb + 0) * RT + col0 + col] = acc0;
    if (mb + 1 < 44) xdT[(mb + 1) * RT + col0 + col] = acc1;
    if (mb + 2 < 44) xdT[(mb + 2) * RT + col0 + col] = acc2;
}

// ---------------------------------------------------------------------------
// K4 (fused): single-kernel two-phase scan with ticket-ordered decoupled
// lookback. Phase A: local scan from h=0, staging dt/g/B/C for ALL 4 chunks
// persistently in LDS (21.6 KB); publish per-thread (P,Hf) packed as one
// 8-byte agent-scope atomic + release flag. Lookback: spin on predecessor
// flags (parallel, one thread per predecessor), then fold aggregates in the
// SAME forward fmaf order as the old scan_part2 (bitwise-identical h_init).
// Phase B: barrier-free rescan straight out of LDS + y epilogue.
// Deadlock-free: tickets are grabbed at block start, and a block only waits
// on smaller tickets (= blocks that already started) -> no dependence on
// dispatch order (G16-safe).
__global__ __launch_bounds__(256) void scan_fused(const float* __restrict__ xdT,
                                                  const float* __restrict__ xcT,
                                                  const float* __restrict__ zsT,
                                                  const float* __restrict__ dtw,
                                                  const float* __restrict__ dtb,
                                                  const float* __restrict__ A_log,
                                                  const float* __restrict__ Dp,
                                                  unsigned long long* __restrict__ agg,
                                                  int* __restrict__ flags,
                                                  int* __restrict__ ticket,
                                                  float* __restrict__ yT) {
    __shared__ float dt_s[4][16][20], g_s[4][16][20], B_s[4][16][20], C_s[4][16][20];
    __shared__ float dtr_s[12][17];
    __shared__ float dtw_s[192];
    __shared__ float dtb_s[16];
    __shared__ int comm;
    int tid = threadIdx.x;
    if (tid == 0) comm = atomicAdd(ticket, 1);
    __syncthreads();
    int t = comm;
    int seg = t / 192;                 // seg-major: earliest blocks take low segs
    int rem = t - seg * 192;
    int dblk = rem % 24, b = rem / 24;
    int d0 = dblk * 16;
    int row0 = b * LL + seg * SEGL;
    int lane = tid & 63;
    int n = lane & 15;
    int dl = ((tid >> 6) << 2) | (lane >> 4);
    int d = d0 + dl;
    int tdd = tid >> 4, ti = tid & 15;
    if (tid < 192) dtw_s[tid] = dtw[d0 * DT_RANK + tid];
    if (tid < 16)  dtb_s[tid] = dtb[d0 + tid];
    float a = -__expf(A_log[d * NS + n]);
    float Dpd = Dp[d];

    // -------- Phase A: local scan from h=0; persist staged tiles per chunk
    float h = 0.f, sdt = 0.f;
    for (int ch = 0; ch < 4; ++ch) {
        int r = row0 + ch * 16;
        float xv = xcT[(d0 + tdd) * RT + r + ti];
        B_s[ch][tdd][ti] = xdT[(12 + tdd) * RT + r + ti];
        C_s[ch][tdd][ti] = xdT[(28 + tdd) * RT + r + ti];
        if (tid < 192) dtr_s[tid >> 4][ti] = xdT[(tid >> 4) * RT + r + ti];
        __syncthreads();     // staging (and, ch=0, dtw_s/dtb_s) ready
        float acc = dtb_s[tdd];
#pragma unroll
        for (int rr = 0; rr < DT_RANK; ++rr)
            acc = fmaf(dtr_s[rr][ti], dtw_s[tdd * DT_RANK + rr], acc);
        float dtv = fmaxf(acc, 0.f) + __logf(1.f + __expf(-fabsf(acc)));
        dt_s[ch][tdd][ti] = dtv;
        g_s[ch][tdd][ti]  = dtv * xv;
        __syncthreads();     // dt_s/g_s ready; dtr_s reads done -> next stage may overwrite
        float dv[16], gb[16];
#pragma unroll
        for (int q = 0; q < 4; ++q) {
            float4 d4 = *(const float4*)&dt_s[ch][dl][q * 4];
            float4 g4 = *(const float4*)&g_s[ch][dl][q * 4];
            float4 b4 = *(const float4*)&B_s[ch][n][q * 4];
            dv[q * 4 + 0] = d4.x; dv[q * 4 + 1] = d4.y;
            dv[q * 4 + 2] = d4.z; dv[q * 4 + 3] = d4.w;
            gb[q * 4 + 0] = g4.x * b4.x; gb[q * 4 + 1] = g4.y * b4.y;
            gb[q * 4 + 2] = g4.z * b4.z; gb[q * 4 + 3] = g4.w * b4.w;
        }
        float eh[16];
#pragma unroll
        for (int i = 0; i < 16; ++i) eh[i] = __expf(dv[i] * a);
#pragma unroll
        for (int i = 0; i < 16; ++i) {
            sdt += dv[i];
            h = fmaf(eh[i], h, gb[i]);
        }
    }

    // -------- Publish aggregate (P, Hf)
    float Pv = __expf(a * sdt);
    union UU { unsigned long long u; struct { float p, hf; } f; };
    UU pk; pk.f.p = Pv; pk.f.hf = h;
    __hip_atomic_store(&agg[(size_t)t * 256 + tid], pk.u,
                       __ATOMIC_RELAXED, __HIP_MEMORY_SCOPE_AGENT);
    __threadfence();
    __syncthreads();     // all threads' agg stores drained (vmcnt(0) at barrier)
    if (tid == 0)
        __hip_atomic_store(&flags[t], 1, __ATOMIC_RELEASE, __HIP_MEMORY_SCOPE_AGENT);

    // -------- Lookback: wait for all predecessors (parallel spin), fold forward
    float h0 = 0.f;
    if (seg > 0) {
        if (tid < seg) {
            int tb = tid * 192 + rem;
            while (__hip_atomic_load(&flags[tb], __ATOMIC_ACQUIRE,
                                     __HIP_MEMORY_SCOPE_AGENT) == 0)
                __builtin_amdgcn_s_sleep(2);
        }
        __syncthreads();
        UU nxt, cur;
        nxt.u = __hip_atomic_load(&agg[(size_t)rem * 256 + tid],
                                  __ATOMIC_RELAXED, __HIP_MEMORY_SCOPE_AGENT);
        for (int s2 = 0; s2 < seg; ++s2) {
            cur = nxt;
            if (s2 + 1 < seg)
                nxt.u = __hip_atomic_load(&agg[(size_t)((s2 + 1) * 192 + rem) * 256 + tid],
                                          __ATOMIC_RELAXED, __HIP_MEMORY_SCOPE_AGENT);
            h0 = fmaf(cur.f.p, h0, cur.f.hf);   // same order as old scan_part2
        }
    }

    // -------- Phase B: rescan from h0, straight out of LDS (no barriers)
    float hb = h0;
    for (int ch = 0; ch < 4; ++ch) {
        int r = row0 + ch * 16;
        float xr = xcT[(size_t)d * RT + r + n];
        float zr = zsT[(size_t)d * RT + r + n];
        float dv[16], gb[16], cv[16];
#pragma unroll
        for (int q = 0; q < 4; ++q) {
            float4 d4 = *(const float4*)&dt_s[ch][dl][q * 4];
            float4 g4 = *(const float4*)&g_s[ch][dl][q * 4];
            float4 b4 = *(const float4*)&B_s[ch][n][q * 4];
            float4 c4 = *(const float4*)&C_s[ch][n][q * 4];
            dv[q * 4 + 0] = d4.x; dv[q * 4 + 1] = d4.y;
            dv[q * 4 + 2] = d4.z; dv[q * 4 + 3] = d4.w;
            gb[q * 4 + 0] = g4.x * b4.x; gb[q * 4 + 1] = g4.y * b4.y;
            gb[q * 4 + 2] = g4.z * b4.z; gb[q * 4 + 3] = g4.w * b4.w;
            cv[q * 4 + 0] = c4.x; cv[q * 4 + 1] = c4.y;
            cv[q * 4 + 2] = c4.z; cv[q * 4 + 3] = c4.w;
        }
        float eh[16];
#pragma unroll
        for (int i = 0; i < 16; ++i) eh[i] = __expf(dv[i] * a);
        float yacc = 0.f;
#pragma unroll
        for (int i = 0; i < 16; ++i) {
            hb = fmaf(eh[i], hb, gb[i]);
            float v = row_sum16(hb * cv[i]);   // sum over n within the 16-lane row
            yacc = (n == i) ? v : yacc;        // lane n keeps step i==n
        }
        yT[(size_t)d * RT + r + n] = fmaf(xr, Dpd, yacc) * zr;
    }
}

// ---------------------------------------------------------------------------
// K5: out[b, c, l] = sum_d yT[d, row] * out_w[c, d]
__global__ __launch_bounds__(256) void gemm_out(const float* __restrict__ yT,
                                                const float* __restrict__ out_w,
                                                float* __restrict__ out) {
    __shared__ float As[16][68];  // [k][row]
    __shared__ float Bs[16][68];  // [k][c]
    int r0 = blockIdx.x * 64;
    int c0 = blockIdx.y * 64;
    int b = r0 >> 10, l0 = r0 & 1023;
    int tid = threadIdx.x;
    int tx = tid & 15;   // -> row
    int ty = tid >> 4;   // -> c
    float acc[4][4] = {};  // [cc][rc]
    for (int k0 = 0; k0 < DI; k0 += 16) {
        {   // A: yT[k0+k, r0+r..] -> As[k][r]
            int k = tid >> 4, r4 = (tid & 15) * 4;
            *(float4*)&As[k][r4] = *(const float4*)&yT[(k0 + k) * RT + r0 + r4];
        }
        {   // B: out_w[c0+c, k0+kc..] -> Bs[kc][c]
            int c = tid >> 2, kc = (tid & 3) * 4;
            float4 v = *(const float4*)&out_w[(c0 + c) * DI + k0 + kc];
            Bs[kc + 0][c] = v.x; Bs[kc + 1][c] = v.y;
            Bs[kc + 2][c] = v.z; Bs[kc + 3][c] = v.w;
        }
        __syncthreads();
#pragma unroll
        for (int k = 0; k < 16; ++k) {
            float4 av = *(const float4*)&As[k][tx * 4];
            float4 bv = *(const float4*)&Bs[k][ty * 4];
            acc[0][0] = fmaf(bv.x, av.x, acc[0][0]);
            acc[0][1] = fmaf(bv.x, av.y, acc[0][1]);
            acc[0][2] = fmaf(bv.x, av.z, acc[0][2]);
            acc[0][3] = fmaf(bv.x, av.w, acc[0][3]);
            acc[1][0] = fmaf(bv.y, av.x, acc[1][0]);
            acc[1][1] = fmaf(bv.y, av.y, acc[1][1]);
            acc[1][2] = fmaf(bv.y, av.z, acc[1][2]);
            acc[1][3] = fmaf(bv.y, av.w, acc[1][3]);
            acc[2][0] = fmaf(bv.z, av.x, acc[2][0]);
            acc[2][1] = fmaf(bv.z, av.y, acc[2][1]);
            acc[2][2] = fmaf(bv.z, av.z, acc[2][2]);
            acc[2][3] = fmaf(bv.z, av.w, acc[2][3]);
            acc[3][0] = fmaf(bv.w, av.x, acc[3][0]);
            acc[3][1] = fmaf(bv.w, av.y, acc[3][1]);
            acc[3][2] = fmaf(bv.w, av.z, acc[3][2]);
            acc[3][3] = fmaf(bv.w, av.w, acc[3][3]);
        }
        __syncthreads();
    }
    float* ob = out + b * CC * LL;
#pragma unroll
    for (int ic = 0; ic < 4; ++ic) {
        float4 o;
        o.x = acc[ic][0]; o.y = acc[ic][1]; o.z = acc[ic][2]; o.w = acc[ic][3];
        *(float4*)&ob[(c0 + ty * 4 + ic) * LL + l0 + tx * 4] = o;
    }
}

// ---------------------------------------------------------------------------
extern "C" void kernel_launch(void* const* d_in, const int* in_sizes, int n_in,
                              void* d_out, int out_size, void* d_ws, size_t ws_size,
                              hipStream_t stream) {
    const float* x         = (const float*)d_in[0];
    const float* proj_w    = (const float*)d_in[1];
    const float* proj_b    = (const float*)d_in[2];
    const float* in_proj_w = (const float*)d_in[3];
    const float* conv_w    = (const float*)d_in[4];
    const float* conv_b    = (const float*)d_in[5];
    const float* xproj_w   = (const float*)d_in[6];
    const float* dtproj_w  = (const float*)d_in[7];
    const float* dtproj_b  = (const float*)d_in[8];
    const float* A_log     = (const float*)d_in[9];
    const float* Dp        = (const float*)d_in[10];
    const float* out_w     = (const float*)d_in[11];
    float* out = (float*)d_out;

    float* ws    = (float*)d_ws;
    float* W2    = ws;                    // 147456
    float* bias2 = W2 + 147456;           // 768
    float* xzT   = bias2 + 768;           // 768*8192 = 6291456 (x raw, z silu'd)
    float* xcT   = xzT + 6291456;         // 3145728
    float* yT    = xcT + 3145728;         // 3145728
    float* xdT   = yT + 3145728;          // 44*8192 = 360448 (0-11 dtr, 12-27 B, 28-43 C)
    unsigned long long* agg = (unsigned long long*)(xdT + 360448);  // 786432 u64 (8B-aligned: even float offset)
    int* flags   = (int*)(xdT + 360448 + 1572864);                  // 3072 ints
    int* ticket  = flags + 3072;                                    // 1 int
    float* zsT   = xzT + DI * RT;         // z half, silu applied by gemm_xz epilogue

    fuse_w_kernel<<<768, 192, 0, stream>>>(in_proj_w, proj_w, proj_b, W2, bias2,
                                           flags, ticket);
    gemm_xz<<<dim3(64, 8), 256, 0, stream>>>(x, W2, bias2, xzT);
    xproj_conv_gemm<<<dim3(128, 2), 512, 0, stream>>>(xzT, conv_w, conv_b,
                                                      xproj_w, xcT, xdT);
    scan_fused<<<3072, 256, 0, stream>>>(xdT, xcT, zsT, dtproj_w, dtproj_b,
                                         A_log, Dp, agg, flags, ticket, yT);
    gemm_out<<<dim3(128, 3), 256, 0, stream>>>(yT, out_w, out);
}

// Round 3
// 241.402 us; speedup vs baseline: 2.2772x; 2.2772x over previous
//
#include <hip/hip_runtime.h>
#include <math.h>

// Problem constants (B=8, C=192, H=W=32)
#define BB 8
#define CC 192
#define LL 1024
#define RT 8192         // total rows = BB*LL
#define DI 384          // d_inner
#define DT_RANK 12
#define NS 16           // D_STATE
#define NSEG 16
#define SEGL 64

// ---------------------------------------------------------------------------
// async global->LDS, 16B per lane. Dest must be linear in lane id within the
// wave (HW uses wave-uniform base + lane*16).
__device__ __forceinline__ void gload_lds16(const float* g, float* l) {
    __builtin_amdgcn_global_load_lds(
        (const __attribute__((address_space(1))) void*)(g),
        (__attribute__((address_space(3))) void*)(l),
        16, 0, 0);
}

// ---------------------------------------------------------------------------
// DPP butterfly sum across a row of 16 lanes (lanes 16k..16k+15).
__device__ __forceinline__ float row_sum16(float v) {
    v += __int_as_float(__builtin_amdgcn_update_dpp(0, __float_as_int(v), 0x140, 0xF, 0xF, true));
    v += __int_as_float(__builtin_amdgcn_update_dpp(0, __float_as_int(v), 0x141, 0xF, 0xF, true));
    v += __int_as_float(__builtin_amdgcn_update_dpp(0, __float_as_int(v), 0x4E,  0xF, 0xF, true));
    v += __int_as_float(__builtin_amdgcn_update_dpp(0, __float_as_int(v), 0xB1,  0xF, 0xF, true));
    return v;
}

// ---------------------------------------------------------------------------
// K1: W2[j,c'] = sum_c in_proj_w[j,c]*proj_w[c,c'];  bias2[j] = in_proj_w[j,:]·proj_b
// Also zero-inits xdT (atomicAdd target of the K-split xproj GEMM; workspace
// is poisoned every iteration so this must happen in-stream).
__global__ void fuse_w_kernel(const float* __restrict__ in_proj_w,
                              const float* __restrict__ proj_w,
                              const float* __restrict__ proj_b,
                              float* __restrict__ W2, float* __restrict__ bias2,
                              float* __restrict__ xdT) {
    int j = blockIdx.x;
    int cp = threadIdx.x;
    int gtid = j * CC + cp;                       // 0..147455
    for (int i = gtid; i < 44 * RT; i += 768 * CC) xdT[i] = 0.f;
    __shared__ float wrow[CC];
    wrow[cp] = in_proj_w[j * CC + cp];
    __syncthreads();
    float acc = 0.f;
#pragma unroll 4
    for (int c = 0; c < CC; ++c) acc = fmaf(wrow[c], proj_w[c * CC + cp], acc);
    W2[j * CC + cp] = acc;
    if (cp == 0) {
        float b = 0.f;
        for (int c = 0; c < CC; ++c) b = fmaf(wrow[c], proj_b[c], b);
        bias2[j] = b;
    }
}

// ---------------------------------------------------------------------------
// K2: xzT[j, row] = sum_c x[b, c, l] * W2[j, c] + bias2[j]   (row = b*1024+l)
// 128 rows x 96 j tile, 256 threads, 6j x (4+4) microtile.
// R3: double-buffered (1 barrier/k-tile), A staged via global_load_lds w=16
// (As unpadded [16][128] -> dest linear in tid; compute reads are 16 distinct
// float4 = 2-way bank alias = free). B prefetched to regs, ds_write after
// compute. z-half blocks (j0>=384) apply silu in epilogue -> zsT directly.
__global__ __launch_bounds__(256) void gemm_xz(const float* __restrict__ x,
                                               const float* __restrict__ W2,
                                               const float* __restrict__ bias2,
                                               float* __restrict__ xzT) {
    __shared__ float As[2][16][128];  // [buf][k][row], linear per buf
    __shared__ float Bs[2][16][100];  // [buf][k][j]
    int r0 = blockIdx.x * 128;
    int j0 = blockIdx.y * 96;
    int b  = r0 >> 10;
    int l0 = r0 & 1023;
    int tid = threadIdx.x;
    int tx = tid & 15;   // row quad (x2, split 64 apart)
    int ty = tid >> 4;   // j sextet
    float acc[6][8] = {};
    const float* xb = x + b * CC * LL;

    // prologue: stage tile 0 into buf 0
#pragma unroll
    for (int it = 0; it < 2; ++it) {
        int idx = tid + it * 256;
        gload_lds16(&xb[(idx >> 5) * LL + l0 + (idx & 31) * 4],
                    ((float*)As[0]) + idx * 4);
    }
#pragma unroll
    for (int it = 0; it < 2; ++it) {
        int idx = tid + it * 256;
        if (idx < 384) {
            int j = idx >> 2, kq = (idx & 3) * 4;
            float4 v = *(const float4*)&W2[(j0 + j) * CC + kq];
            Bs[0][kq + 0][j] = v.x; Bs[0][kq + 1][j] = v.y;
            Bs[0][kq + 2][j] = v.z; Bs[0][kq + 3][j] = v.w;
        }
    }
    __syncthreads();   // drains vmcnt (gload_lds) + lgkm (ds_write)

    for (int t = 0; t < 12; ++t) {
        int cur = t & 1, nxt = cur ^ 1;
        float4 breg[2];
        if (t < 11) {
            int k0n = (t + 1) * 16;
#pragma unroll
            for (int it = 0; it < 2; ++it) {     // A(t+1): async into other buf
                int idx = tid + it * 256;
                gload_lds16(&xb[(k0n + (idx >> 5)) * LL + l0 + (idx & 31) * 4],
                            ((float*)As[nxt]) + idx * 4);
            }
#pragma unroll
            for (int it = 0; it < 2; ++it) {     // B(t+1): global -> regs
                int idx = tid + it * 256;
                if (idx < 384)
                    breg[it] = *(const float4*)&W2[(j0 + (idx >> 2)) * CC + k0n + (idx & 3) * 4];
            }
        }
        // compute tile t from buf cur
#pragma unroll
        for (int k = 0; k < 16; ++k) {
            float4 a0 = *(const float4*)&As[cur][k][tx * 4];
            float4 a1 = *(const float4*)&As[cur][k][64 + tx * 4];
            float ar[8] = {a0.x, a0.y, a0.z, a0.w, a1.x, a1.y, a1.z, a1.w};
            float br[6];
#pragma unroll
            for (int q = 0; q < 6; ++q) br[q] = Bs[cur][k][ty * 6 + q];
#pragma unroll
            for (int jc = 0; jc < 6; ++jc)
#pragma unroll
                for (int rc = 0; rc < 8; ++rc)
                    acc[jc][rc] = fmaf(br[jc], ar[rc], acc[jc][rc]);
        }
        if (t < 11) {
#pragma unroll
            for (int it = 0; it < 2; ++it) {     // B(t+1): regs -> other buf
                int idx = tid + it * 256;
                if (idx < 384) {
                    int j = idx >> 2, kq = (idx & 3) * 4;
                    Bs[nxt][kq + 0][j] = breg[it].x; Bs[nxt][kq + 1][j] = breg[it].y;
                    Bs[nxt][kq + 2][j] = breg[it].z; Bs[nxt][kq + 3][j] = breg[it].w;
                }
            }
        }
        __syncthreads();   // next tile fully staged; cur buf free for overwrite
    }

    bool is_z = (j0 >= DI);
#pragma unroll
    for (int jc = 0; jc < 6; ++jc) {
        int j = j0 + ty * 6 + jc;
        float bval = bias2[j];
        float o[8];
#pragma unroll
        for (int rc = 0; rc < 8; ++rc) o[rc] = acc[jc][rc] + bval;
        if (is_z) {
#pragma unroll
            for (int rc = 0; rc < 8; ++rc)
                o[rc] = __fdividef(o[rc], 1.f + __expf(-o[rc]));
        }
        float4 o0 = make_float4(o[0], o[1], o[2], o[3]);
        float4 o1 = make_float4(o[4], o[5], o[6], o[7]);
        *(float4*)&xzT[j * RT + r0 + tx * 4]      = o0;
        *(float4*)&xzT[j * RT + r0 + 64 + tx * 4] = o1;
    }
}

// ---------------------------------------------------------------------------
// K3: skinny GEMM with fused causal depthwise conv (k=4) + silu in staging.
// R3: K-SPLIT instead of M-split. blockIdx.y picks channel range
// [y*192, y*192+192): staging (conv+silu) and xzT reads are done ONCE per
// channel (was twice); xcT writes partitioned. Partial sums combined via
// atomicAdd into pre-zeroed xdT (exactly 2 contributors -> deterministic).
// Each of 8 thread-groups handles 6 of the 44 M-rows. grid (128,2), 512 thr.
__global__ __launch_bounds__(512) void xproj_conv_gemm(const float* __restrict__ xzT,
                                                       const float* __restrict__ conv_w,
                                                       const float* __restrict__ conv_b,
                                                       const float* __restrict__ aw,
                                                       float* __restrict__ xcT,
                                                       float* __restrict__ xdT) {
    __shared__ float Bs[32][64];
    int col0 = blockIdx.x * 64;
    int kbase = blockIdx.y * 192;
    int tid = threadIdx.x;
    int col = tid & 63, mg = tid >> 6;          // mg wave-uniform -> scalar A loads
    int mb = mg * 6;                             // rows mb..mb+5 (44..47 discarded)
    const float* ar[6];
#pragma unroll
    for (int m = 0; m < 6; ++m) ar[m] = aw + min(mb + m, 43) * DI + kbase;
    float acc[6] = {};
    int ks = tid >> 4, c4 = (tid & 15) * 4;
    bool atL0 = ((col0 & 1023) == 0) && (c4 == 0);   // conv zero-pad boundary
    for (int k0 = 0; k0 < 192; k0 += 32) {
        int dch = kbase + k0 + ks;
        const float* src = xzT + (size_t)dch * RT + col0 + c4;
        float4 cur = *(const float4*)src;
        float4 prev = make_float4(0.f, 0.f, 0.f, 0.f);
        if (!atL0) prev = *(const float4*)(src - 4);
        float4 w4 = *(const float4*)&conv_w[dch * 4];   // w0=x w1=y w2=z w3=w
        float bb = conv_b[dch];
        float v0 = bb + w4.w * cur.x + w4.z * prev.w + w4.y * prev.z + w4.x * prev.y;
        float v1 = bb + w4.w * cur.y + w4.z * cur.x  + w4.y * prev.w + w4.x * prev.z;
        float v2 = bb + w4.w * cur.z + w4.z * cur.y  + w4.y * cur.x  + w4.x * prev.w;
        float v3 = bb + w4.w * cur.w + w4.z * cur.z  + w4.y * cur.y  + w4.x * cur.x;
        float4 o;
        o.x = __fdividef(v0, 1.f + __expf(-v0));
        o.y = __fdividef(v1, 1.f + __expf(-v1));
        o.z = __fdividef(v2, 1.f + __expf(-v2));
        o.w = __fdividef(v3, 1.f + __expf(-v3));
        *(float4*)&Bs[ks][c4] = o;
        *(float4*)&xcT[(size_t)dch * RT + col0 + c4] = o;   // own channel range
        __syncthreads();
#pragma unroll
        for (int k = 0; k < 32; ++k) {
            float bv = Bs[k][col];
#pragma unroll
            for (int m = 0; m < 6; ++m)
                acc[m] = fmaf(ar[m][k0 + k], bv, acc[m]);
        }
        __syncthreads();
    }
#pragma unroll
    for (int m = 0; m < 6; ++m)
        if (mb + m < 44)
            atomicAdd(&xdT[(mb + m) * RT + col0 + col], acc[m]);
}

// ---------------------------------------------------------------------------
// K4a: per-segment scan from h=0; dt computed inline from dtr rows of xdT.
// Emits P = exp(a*sum(dt)) (== prod(dA)), Hf = final h.
// grid (16 seg, 24 dblk, 8 b), block 256.  (R1-proven version.)
__global__ __launch_bounds__(256) void scan_part1(const float* __restrict__ xdT,
                                                  const float* __restrict__ xcT,
                                                  const float* __restrict__ dtw,
                                                  const float* __restrict__ dtb,
                                                  const float* __restrict__ A_log,
                                                  float* __restrict__ P,
                                                  float* __restrict__ Hf) {
    __shared__ float dt_s[16][20], g_s[16][20], B_s[16][20];
    __shared__ float dtr_s[12][17];
    __shared__ float dtw_s[192];
    __shared__ float dtb_s[16];
    int seg = blockIdx.x, d0 = blockIdx.y * 16, b = blockIdx.z;
    int row0 = b * LL + seg * SEGL;
    int tid = threadIdx.x;
    int lane = tid & 63;
    int n = lane & 15;
    int dl = ((tid >> 6) << 2) | (lane >> 4);
    int tdd = tid >> 4, ti = tid & 15;
    if (tid < 192) dtw_s[tid] = dtw[d0 * DT_RANK + tid];
    if (tid < 16)  dtb_s[tid] = dtb[d0 + tid];
    float a = -__expf(A_log[(d0 + dl) * NS + n]);
    float h = 0.f, sdt = 0.f;
    for (int ch = 0; ch < 4; ++ch) {
        int r = row0 + ch * 16;
        float xv = xcT[(d0 + tdd) * RT + r + ti];
        B_s[tdd][ti] = xdT[(12 + tdd) * RT + r + ti];
        if (tid < 192) dtr_s[tid >> 4][ti] = xdT[(tid >> 4) * RT + r + ti];
        __syncthreads();     // staging ready (prev chunk's preloads done)
        float acc = dtb_s[tdd];
#pragma unroll
        for (int rr = 0; rr < DT_RANK; ++rr)
            acc = fmaf(dtr_s[rr][ti], dtw_s[tdd * DT_RANK + rr], acc);
        float dtv = fmaxf(acc, 0.f) + __logf(1.f + __expf(-fabsf(acc)));
        dt_s[tdd][ti] = dtv;
        g_s[tdd][ti]  = dtv * xv;
        __syncthreads();     // dt_s/g_s ready
        float dv[16], gb[16];
#pragma unroll
        for (int q = 0; q < 4; ++q) {
            float4 d4 = *(const float4*)&dt_s[dl][q * 4];   // broadcast within row
            float4 g4 = *(const float4*)&g_s[dl][q * 4];
            float4 b4 = *(const float4*)&B_s[n][q * 4];
            dv[q * 4 + 0] = d4.x; dv[q * 4 + 1] = d4.y;
            dv[q * 4 + 2] = d4.z; dv[q * 4 + 3] = d4.w;
            gb[q * 4 + 0] = g4.x * b4.x; gb[q * 4 + 1] = g4.y * b4.y;
            gb[q * 4 + 2] = g4.z * b4.z; gb[q * 4 + 3] = g4.w * b4.w;
        }
        __syncthreads();     // preload done -> next chunk may overwrite LDS
        float eh[16];
#pragma unroll
        for (int i = 0; i < 16; ++i) eh[i] = __expf(dv[i] * a);
#pragma unroll
        for (int i = 0; i < 16; ++i) {
            sdt += dv[i];
            h = fmaf(eh[i], h, gb[i]);
        }
    }
    int idx = ((seg * BB + b) * DI + d0 + dl) * NS + n;
    P[idx] = __expf(a * sdt);
    Hf[idx] = h;
}

// ---------------------------------------------------------------------------
// K4b: rescan each segment; h_init computed in-block by folding the earlier
// segments' (P,Hf) summaries. DPP row-of-16 butterfly for the n-reduction.
// (R1-proven version.)
__global__ __launch_bounds__(256) void scan_part2(const float* __restrict__ xdT,
                                                  const float* __restrict__ xcT,
                                                  const float* __restrict__ zsT,
                                                  const float* __restrict__ dtw,
                                                  const float* __restrict__ dtb,
                                                  const float* __restrict__ P,
                                                  const float* __restrict__ Hf,
                                                  const float* __restrict__ A_log,
                                                  const float* __restrict__ Dp,
                                                  float* __restrict__ yT) {
    __shared__ float dt_s[16][20], g_s[16][20], B_s[16][20], C_s[16][20];
    __shared__ float dtr_s[12][17];
    __shared__ float dtw_s[192];
    __shared__ float dtb_s[16];
    int seg = blockIdx.x, d0 = blockIdx.y * 16, b = blockIdx.z;
    int row0 = b * LL + seg * SEGL;
    int tid = threadIdx.x;
    int lane = tid & 63;
    int n = lane & 15;
    int dl = ((tid >> 6) << 2) | (lane >> 4);
    int d = d0 + dl;
    int tdd = tid >> 4, ti = tid & 15;
    if (tid < 192) dtw_s[tid] = dtw[d0 * DT_RANK + tid];
    if (tid < 16)  dtb_s[tid] = dtb[d0 + tid];
    float a = -__expf(A_log[d * NS + n]);
    float Dpd = Dp[d];
    // h_init: fold earlier segments' summaries (coalesced loads)
    float h = 0.f;
    for (int s = 0; s < seg; ++s) {
        int off = ((s * BB + b) * DI + d) * NS + n;
        h = fmaf(P[off], h, Hf[off]);
    }
    for (int ch = 0; ch < 4; ++ch) {
        int r = row0 + ch * 16;
        // epilogue operands for the (dl,n) writer role (L1/L2-resident)
        float xr = xcT[(size_t)d * RT + r + n];
        float zr = zsT[(size_t)d * RT + r + n];
        // staging role (tdd,ti)
        float xv = xcT[(d0 + tdd) * RT + r + ti];
        B_s[tdd][ti] = xdT[(12 + tdd) * RT + r + ti];
        C_s[tdd][ti] = xdT[(28 + tdd) * RT + r + ti];
        if (tid < 192) dtr_s[tid >> 4][ti] = xdT[(tid >> 4) * RT + r + ti];
        __syncthreads();     // staging ready
        float acc = dtb_s[tdd];
#pragma unroll
        for (int rr = 0; rr < DT_RANK; ++rr)
            acc = fmaf(dtr_s[rr][ti], dtw_s[tdd * DT_RANK + rr], acc);
        float dtv = fmaxf(acc, 0.f) + __logf(1.f + __expf(-fabsf(acc)));
        dt_s[tdd][ti] = dtv;
        g_s[tdd][ti]  = dtv * xv;
        __syncthreads();     // dt_s/g_s ready
        float dv[16], gb[16], cv[16];
#pragma unroll
        for (int q = 0; q < 4; ++q) {
            float4 d4 = *(const float4*)&dt_s[dl][q * 4];
            float4 g4 = *(const float4*)&g_s[dl][q * 4];
            float4 b4 = *(const float4*)&B_s[n][q * 4];
            float4 c4 = *(const float4*)&C_s[n][q * 4];
            dv[q * 4 + 0] = d4.x; dv[q * 4 + 1] = d4.y;
            dv[q * 4 + 2] = d4.z; dv[q * 4 + 3] = d4.w;
            gb[q * 4 + 0] = g4.x * b4.x; gb[q * 4 + 1] = g4.y * b4.y;
            gb[q * 4 + 2] = g4.z * b4.z; gb[q * 4 + 3] = g4.w * b4.w;
            cv[q * 4 + 0] = c4.x; cv[q * 4 + 1] = c4.y;
            cv[q * 4 + 2] = c4.z; cv[q * 4 + 3] = c4.w;
        }
        __syncthreads();     // preload done -> next chunk may overwrite LDS
        float eh[16];
#pragma unroll
        for (int i = 0; i < 16; ++i) eh[i] = __expf(dv[i] * a);
        float yacc = 0.f;
#pragma unroll
        for (int i = 0; i < 16; ++i) {
            h = fmaf(eh[i], h, gb[i]);
            float v = row_sum16(h * cv[i]);   // sum over n within the 16-lane row
            yacc = (n == i) ? v : yacc;       // lane n keeps step i==n
        }
        yT[(size_t)d * RT + r + n] = fmaf(xr, Dpd, yacc) * zr;
    }
}

// ---------------------------------------------------------------------------
// K5: out[b, c, l] = sum_d yT[d, row] * out_w[c, d]
// 64x64 tile, 4x4 microtile, 256 threads. grid (128, 3).
// R3: As unpadded [16][64] (staging linear in tid) staged via global_load_lds.
__global__ __launch_bounds__(256) void gemm_out(const float* __restrict__ yT,
                                                const float* __restrict__ out_w,
                                                float* __restrict__ out) {
    __shared__ float As[16][64];  // [k][row], linear
    __shared__ float Bs[16][68];  // [k][c]
    int r0 = blockIdx.x * 64;
    int c0 = blockIdx.y * 64;
    int b = r0 >> 10, l0 = r0 & 1023;
    int tid = threadIdx.x;
    int tx = tid & 15;   // -> row
    int ty = tid >> 4;   // -> c
    float acc[4][4] = {};  // [cc][rc]
    for (int k0 = 0; k0 < DI; k0 += 16) {
        {   // A: yT[k0+k, r0+r..] -> As linear (k*64 + r4 == tid*4)
            gload_lds16(&yT[(k0 + (tid >> 4)) * RT + r0 + (tid & 15) * 4],
                        ((float*)As) + tid * 4);
        }
        {   // B: out_w[c0+c, k0+kc..] -> Bs[kc][c]
            int c = tid >> 2, kc = (tid & 3) * 4;
            float4 v = *(const float4*)&out_w[(c0 + c) * DI + k0 + kc];
            Bs[kc + 0][c] = v.x; Bs[kc + 1][c] = v.y;
            Bs[kc + 2][c] = v.z; Bs[kc + 3][c] = v.w;
        }
        __syncthreads();
#pragma unroll
        for (int k = 0; k < 16; ++k) {
            float4 av = *(const float4*)&As[k][tx * 4];
            float4 bv = *(const float4*)&Bs[k][ty * 4];
            acc[0][0] = fmaf(bv.x, av.x, acc[0][0]);
            acc[0][1] = fmaf(bv.x, av.y, acc[0][1]);
            acc[0][2] = fmaf(bv.x, av.z, acc[0][2]);
            acc[0][3] = fmaf(bv.x, av.w, acc[0][3]);
            acc[1][0] = fmaf(bv.y, av.x, acc[1][0]);
            acc[1][1] = fmaf(bv.y, av.y, acc[1][1]);
            acc[1][2] = fmaf(bv.y, av.z, acc[1][2]);
            acc[1][3] = fmaf(bv.y, av.w, acc[1][3]);
            acc[2][0] = fmaf(bv.z, av.x, acc[2][0]);
            acc[2][1] = fmaf(bv.z, av.y, acc[2][1]);
            acc[2][2] = fmaf(bv.z, av.z, acc[2][2]);
            acc[2][3] = fmaf(bv.z, av.w, acc[2][3]);
            acc[3][0] = fmaf(bv.w, av.x, acc[3][0]);
            acc[3][1] = fmaf(bv.w, av.y, acc[3][1]);
            acc[3][2] = fmaf(bv.w, av.z, acc[3][2]);
            acc[3][3] = fmaf(bv.w, av.w, acc[3][3]);
        }
        __syncthreads();
    }
    float* ob = out + b * CC * LL;
#pragma unroll
    for (int ic = 0; ic < 4; ++ic) {
        float4 o;
        o.x = acc[ic][0]; o.y = acc[ic][1]; o.z = acc[ic][2]; o.w = acc[ic][3];
        *(float4*)&ob[(c0 + ty * 4 + ic) * LL + l0 + tx * 4] = o;
    }
}

// ---------------------------------------------------------------------------
extern "C" void kernel_launch(void* const* d_in, const int* in_sizes, int n_in,
                              void* d_out, int out_size, void* d_ws, size_t ws_size,
                              hipStream_t stream) {
    const float* x         = (const float*)d_in[0];
    const float* proj_w    = (const float*)d_in[1];
    const float* proj_b    = (const float*)d_in[2];
    const float* in_proj_w = (const float*)d_in[3];
    const float* conv_w    = (const float*)d_in[4];
    const float* conv_b    = (const float*)d_in[5];
    const float* xproj_w   = (const float*)d_in[6];
    const float* dtproj_w  = (const float*)d_in[7];
    const float* dtproj_b  = (const float*)d_in[8];
    const float* A_log     = (const float*)d_in[9];
    const float* Dp        = (const float*)d_in[10];
    const float* out_w     = (const float*)d_in[11];
    float* out = (float*)d_out;

    float* ws    = (float*)d_ws;
    float* W2    = ws;                    // 147456
    float* bias2 = W2 + 147456;           // 768
    float* xzT   = bias2 + 768;           // 768*8192 = 6291456 (x raw, z silu'd)
    float* xcT   = xzT + 6291456;         // 3145728
    float* yT    = xcT + 3145728;         // 3145728
    float* xdT   = yT + 3145728;          // 44*8192 = 360448 (0-11 dtr, 12-27 B, 28-43 C)
    float* P     = xdT + 360448;          // 786432
    float* Hf    = P + 786432;            // 786432
    float* zsT   = xzT + DI * RT;         // z half, silu applied by gemm_xz epilogue

    fuse_w_kernel<<<768, 192, 0, stream>>>(in_proj_w, proj_w, proj_b, W2, bias2, xdT);
    gemm_xz<<<dim3(64, 8), 256, 0, stream>>>(x, W2, bias2, xzT);
    xproj_conv_gemm<<<dim3(128, 2), 512, 0, stream>>>(xzT, conv_w, conv_b,
                                                      xproj_w, xcT, xdT);
    scan_part1<<<dim3(16, 24, 8), 256, 0, stream>>>(xdT, xcT, dtproj_w, dtproj_b,
                                                    A_log, P, Hf);
    scan_part2<<<dim3(16, 24, 8), 256, 0, stream>>>(xdT, xcT, zsT, dtproj_w, dtproj_b,
                                                    P, Hf, A_log, Dp, yT);
    gemm_out<<<dim3(128, 3), 256, 0, stream>>>(yT, out_w, out);
}

// Round 5
// 230.343 us; speedup vs baseline: 2.3865x; 1.0480x over previous
//
#include <hip/hip_runtime.h>
#include <math.h>

// Problem constants (B=8, C=192, H=W=32)
#define BB 8
#define CC 192
#define LL 1024
#define RT 8192         // total rows = BB*LL
#define DI 384          // d_inner
#define DT_RANK 12
#define NS 16           // D_STATE
#define NSEG 16
#define SEGL 64

// ---------------------------------------------------------------------------
// async global->LDS, 16B per lane. Dest must be linear in lane id within the
// wave (HW uses wave-uniform base + lane*16).
__device__ __forceinline__ void gload_lds16(const float* g, float* l) {
    __builtin_amdgcn_global_load_lds(
        (const __attribute__((address_space(1))) void*)(g),
        (__attribute__((address_space(3))) void*)(l),
        16, 0, 0);
}

// ---------------------------------------------------------------------------
// DPP butterfly sum across a row of 16 lanes (lanes 16k..16k+15).
__device__ __forceinline__ float row_sum16(float v) {
    v += __int_as_float(__builtin_amdgcn_update_dpp(0, __float_as_int(v), 0x140, 0xF, 0xF, true));
    v += __int_as_float(__builtin_amdgcn_update_dpp(0, __float_as_int(v), 0x141, 0xF, 0xF, true));
    v += __int_as_float(__builtin_amdgcn_update_dpp(0, __float_as_int(v), 0x4E,  0xF, 0xF, true));
    v += __int_as_float(__builtin_amdgcn_update_dpp(0, __float_as_int(v), 0xB1,  0xF, 0xF, true));
    return v;
}

// ---------------------------------------------------------------------------
// K1: W2[j,c'] = sum_c in_proj_w[j,c]*proj_w[c,c'];  bias2[j] = in_proj_w[j,:]·proj_b
// Also zero-inits xdT (atomicAdd target of the K-split xproj GEMM).
__global__ void fuse_w_kernel(const float* __restrict__ in_proj_w,
                              const float* __restrict__ proj_w,
                              const float* __restrict__ proj_b,
                              float* __restrict__ W2, float* __restrict__ bias2,
                              float* __restrict__ xdT) {
    int j = blockIdx.x;
    int cp = threadIdx.x;
    int gtid = j * CC + cp;                       // 0..147455
    for (int i = gtid; i < 44 * RT; i += 768 * CC) xdT[i] = 0.f;
    __shared__ float wrow[CC];
    wrow[cp] = in_proj_w[j * CC + cp];
    __syncthreads();
    float acc = 0.f;
#pragma unroll 4
    for (int c = 0; c < CC; ++c) acc = fmaf(wrow[c], proj_w[c * CC + cp], acc);
    W2[j * CC + cp] = acc;
    if (cp == 0) {
        float b = 0.f;
        for (int c = 0; c < CC; ++c) b = fmaf(wrow[c], proj_b[c], b);
        bias2[j] = b;
    }
}

// ---------------------------------------------------------------------------
// K2: xzT[j, row] = sum_c x[b, c, l] * W2[j, c] + bias2[j]   (row = b*1024+l)
// R4b: occupancy-first retile (R4 structure, B-staging bug fixed: 384 float4
// loads need TWO passes of 256 threads — R4's single pass left j in [64,96)
// unstaged -> absmax 11). 96j x 64r tile, grid (128,8) = 1024 blocks
// = 4 blocks/CU = 16 waves/CU. Single-buffered 10.25 KB LDS; A staged via
// global_load_lds w=16 into linear As; Bs padded to 100. Microtile 6j x 4r.
// z-half blocks (j0>=384) apply silu in epilogue -> zsT directly.
__global__ __launch_bounds__(256) void gemm_xz(const float* __restrict__ x,
                                               const float* __restrict__ W2,
                                               const float* __restrict__ bias2,
                                               float* __restrict__ xzT) {
    __shared__ float As[16][64];    // [k][row], linear for gload_lds
    __shared__ float Bs[16][100];   // [k][j], padded
    int r0 = blockIdx.x * 64;
    int j0 = blockIdx.y * 96;
    int b  = r0 >> 10;
    int l0 = r0 & 1023;
    int tid = threadIdx.x;
    int tx = tid & 15;   // row quad
    int ty = tid >> 4;   // j sextet
    float acc[6][4] = {};
    const float* xb = x + b * CC * LL;
    for (int t = 0; t < 12; ++t) {
        int k0 = t * 16;
        // A: 16k x 64r = 256 float4, one per thread, dest linear in tid
        gload_lds16(&xb[(k0 + (tid >> 4)) * LL + l0 + (tid & 15) * 4],
                    ((float*)As) + tid * 4);
        // B: 96j x 16k = 384 float4, two passes of 256 threads (transpose)
#pragma unroll
        for (int it = 0; it < 2; ++it) {
            int idx = tid + it * 256;
            if (idx < 384) {
                int j = idx >> 2, kq = (idx & 3) * 4;
                float4 v = *(const float4*)&W2[(j0 + j) * CC + k0 + kq];
                Bs[kq + 0][j] = v.x; Bs[kq + 1][j] = v.y;
                Bs[kq + 2][j] = v.z; Bs[kq + 3][j] = v.w;
            }
        }
        __syncthreads();   // drains vmcnt (gload_lds) + lgkm (ds_write)
#pragma unroll
        for (int k = 0; k < 16; ++k) {
            float4 av = *(const float4*)&As[k][tx * 4];
            float2 b01 = *(const float2*)&Bs[k][ty * 6];
            float2 b23 = *(const float2*)&Bs[k][ty * 6 + 2];
            float2 b45 = *(const float2*)&Bs[k][ty * 6 + 4];
            float br[6] = {b01.x, b01.y, b23.x, b23.y, b45.x, b45.y};
            float ar[4] = {av.x, av.y, av.z, av.w};
#pragma unroll
            for (int jc = 0; jc < 6; ++jc)
#pragma unroll
                for (int rc = 0; rc < 4; ++rc)
                    acc[jc][rc] = fmaf(br[jc], ar[rc], acc[jc][rc]);
        }
        __syncthreads();
    }
    bool is_z = (j0 >= DI);
#pragma unroll
    for (int jc = 0; jc < 6; ++jc) {
        int j = j0 + ty * 6 + jc;
        float bval = bias2[j];
        float o[4];
#pragma unroll
        for (int rc = 0; rc < 4; ++rc) o[rc] = acc[jc][rc] + bval;
        if (is_z) {
#pragma unroll
            for (int rc = 0; rc < 4; ++rc)
                o[rc] = __fdividef(o[rc], 1.f + __expf(-o[rc]));
        }
        *(float4*)&xzT[j * RT + r0 + tx * 4] = make_float4(o[0], o[1], o[2], o[3]);
    }
}

// ---------------------------------------------------------------------------
// K3: skinny GEMM with fused causal depthwise conv (k=4) + silu in staging.
// K-split: blockIdx.y picks channel range [y*192, y*192+192); staging and
// xzT reads done once per channel; partial sums via atomicAdd into
// pre-zeroed xdT (exactly 2 contributors -> deterministic). (R3-proven.)
__global__ __launch_bounds__(512) void xproj_conv_gemm(const float* __restrict__ xzT,
                                                       const float* __restrict__ conv_w,
                                                       const float* __restrict__ conv_b,
                                                       const float* __restrict__ aw,
                                                       float* __restrict__ xcT,
                                                       float* __restrict__ xdT) {
    __shared__ float Bs[32][64];
    int col0 = blockIdx.x * 64;
    int kbase = blockIdx.y * 192;
    int tid = threadIdx.x;
    int col = tid & 63, mg = tid >> 6;          // mg wave-uniform -> scalar A loads
    int mb = mg * 6;                             // rows mb..mb+5 (44..47 discarded)
    const float* ar[6];
#pragma unroll
    for (int m = 0; m < 6; ++m) ar[m] = aw + min(mb + m, 43) * DI + kbase;
    float acc[6] = {};
    int ks = tid >> 4, c4 = (tid & 15) * 4;
    bool atL0 = ((col0 & 1023) == 0) && (c4 == 0);   // conv zero-pad boundary
    for (int k0 = 0; k0 < 192; k0 += 32) {
        int dch = kbase + k0 + ks;
        const float* src = xzT + (size_t)dch * RT + col0 + c4;
        float4 cur = *(const float4*)src;
        float4 prev = make_float4(0.f, 0.f, 0.f, 0.f);
        if (!atL0) prev = *(const float4*)(src - 4);
        float4 w4 = *(const float4*)&conv_w[dch * 4];   // w0=x w1=y w2=z w3=w
        float bb = conv_b[dch];
        float v0 = bb + w4.w * cur.x + w4.z * prev.w + w4.y * prev.z + w4.x * prev.y;
        float v1 = bb + w4.w * cur.y + w4.z * cur.x  + w4.y * prev.w + w4.x * prev.z;
        float v2 = bb + w4.w * cur.z + w4.z * cur.y  + w4.y * cur.x  + w4.x * prev.w;
        float v3 = bb + w4.w * cur.w + w4.z * cur.z  + w4.y * cur.y  + w4.x * cur.x;
        float4 o;
        o.x = __fdividef(v0, 1.f + __expf(-v0));
        o.y = __fdividef(v1, 1.f + __expf(-v1));
        o.z = __fdividef(v2, 1.f + __expf(-v2));
        o.w = __fdividef(v3, 1.f + __expf(-v3));
        *(float4*)&Bs[ks][c4] = o;
        *(float4*)&xcT[(size_t)dch * RT + col0 + c4] = o;   // own channel range
        __syncthreads();
#pragma unroll
        for (int k = 0; k < 32; ++k) {
            float bv = Bs[k][col];
#pragma unroll
            for (int m = 0; m < 6; ++m)
                acc[m] = fmaf(ar[m][k0 + k], bv, acc[m]);
        }
        __syncthreads();
    }
#pragma unroll
    for (int m = 0; m < 6; ++m)
        if (mb + m < 44)
            atomicAdd(&xdT[(mb + m) * RT + col0 + col], acc[m]);
}

// ---------------------------------------------------------------------------
// K4a: per-segment scan from h=0; dt computed inline from dtr rows of xdT.
// Emits P = exp(a*sum(dt)) (== prod(dA)), Hf = final h.
// grid (16 seg, 24 dblk, 8 b), block 256.  (R1-proven version.)
__global__ __launch_bounds__(256) void scan_part1(const float* __restrict__ xdT,
                                                  const float* __restrict__ xcT,
                                                  const float* __restrict__ dtw,
                                                  const float* __restrict__ dtb,
                                                  const float* __restrict__ A_log,
                                                  float* __restrict__ P,
                                                  float* __restrict__ Hf) {
    __shared__ float dt_s[16][20], g_s[16][20], B_s[16][20];
    __shared__ float dtr_s[12][17];
    __shared__ float dtw_s[192];
    __shared__ float dtb_s[16];
    int seg = blockIdx.x, d0 = blockIdx.y * 16, b = blockIdx.z;
    int row0 = b * LL + seg * SEGL;
    int tid = threadIdx.x;
    int lane = tid & 63;
    int n = lane & 15;
    int dl = ((tid >> 6) << 2) | (lane >> 4);
    int tdd = tid >> 4, ti = tid & 15;
    if (tid < 192) dtw_s[tid] = dtw[d0 * DT_RANK + tid];
    if (tid < 16)  dtb_s[tid] = dtb[d0 + tid];
    float a = -__expf(A_log[(d0 + dl) * NS + n]);
    float h = 0.f, sdt = 0.f;
    for (int ch = 0; ch < 4; ++ch) {
        int r = row0 + ch * 16;
        float xv = xcT[(d0 + tdd) * RT + r + ti];
        B_s[tdd][ti] = xdT[(12 + tdd) * RT + r + ti];
        if (tid < 192) dtr_s[tid >> 4][ti] = xdT[(tid >> 4) * RT + r + ti];
        __syncthreads();     // staging ready (prev chunk's preloads done)
        float acc = dtb_s[tdd];
#pragma unroll
        for (int rr = 0; rr < DT_RANK; ++rr)
            acc = fmaf(dtr_s[rr][ti], dtw_s[tdd * DT_RANK + rr], acc);
        float dtv = fmaxf(acc, 0.f) + __logf(1.f + __expf(-fabsf(acc)));
        dt_s[tdd][ti] = dtv;
        g_s[tdd][ti]  = dtv * xv;
        __syncthreads();     // dt_s/g_s ready
        float dv[16], gb[16];
#pragma unroll
        for (int q = 0; q < 4; ++q) {
            float4 d4 = *(const float4*)&dt_s[dl][q * 4];   // broadcast within row
            float4 g4 = *(const float4*)&g_s[dl][q * 4];
            float4 b4 = *(const float4*)&B_s[n][q * 4];
            dv[q * 4 + 0] = d4.x; dv[q * 4 + 1] = d4.y;
            dv[q * 4 + 2] = d4.z; dv[q * 4 + 3] = d4.w;
            gb[q * 4 + 0] = g4.x * b4.x; gb[q * 4 + 1] = g4.y * b4.y;
            gb[q * 4 + 2] = g4.z * b4.z; gb[q * 4 + 3] = g4.w * b4.w;
        }
        __syncthreads();     // preload done -> next chunk may overwrite LDS
        float eh[16];
#pragma unroll
        for (int i = 0; i < 16; ++i) eh[i] = __expf(dv[i] * a);
#pragma unroll
        for (int i = 0; i < 16; ++i) {
            sdt += dv[i];
            h = fmaf(eh[i], h, gb[i]);
        }
    }
    int idx = ((seg * BB + b) * DI + d0 + dl) * NS + n;
    P[idx] = __expf(a * sdt);
    Hf[idx] = h;
}

// ---------------------------------------------------------------------------
// K4b: rescan each segment; h_init computed in-block by folding the earlier
// segments' (P,Hf) summaries. DPP row-of-16 butterfly for the n-reduction.
// (R1-proven version.)
__global__ __launch_bounds__(256) void scan_part2(const float* __restrict__ xdT,
                                                  const float* __restrict__ xcT,
                                                  const float* __restrict__ zsT,
                                                  const float* __restrict__ dtw,
                                                  const float* __restrict__ dtb,
                                                  const float* __restrict__ P,
                                                  const float* __restrict__ Hf,
                                                  const float* __restrict__ A_log,
                                                  const float* __restrict__ Dp,
                                                  float* __restrict__ yT) {
    __shared__ float dt_s[16][20], g_s[16][20], B_s[16][20], C_s[16][20];
    __shared__ float dtr_s[12][17];
    __shared__ float dtw_s[192];
    __shared__ float dtb_s[16];
    int seg = blockIdx.x, d0 = blockIdx.y * 16, b = blockIdx.z;
    int row0 = b * LL + seg * SEGL;
    int tid = threadIdx.x;
    int lane = tid & 63;
    int n = lane & 15;
    int dl = ((tid >> 6) << 2) | (lane >> 4);
    int d = d0 + dl;
    int tdd = tid >> 4, ti = tid & 15;
    if (tid < 192) dtw_s[tid] = dtw[d0 * DT_RANK + tid];
    if (tid < 16)  dtb_s[tid] = dtb[d0 + tid];
    float a = -__expf(A_log[d * NS + n]);
    float Dpd = Dp[d];
    // h_init: fold earlier segments' summaries (coalesced loads)
    float h = 0.f;
    for (int s = 0; s < seg; ++s) {
        int off = ((s * BB + b) * DI + d) * NS + n;
        h = fmaf(P[off], h, Hf[off]);
    }
    for (int ch = 0; ch < 4; ++ch) {
        int r = row0 + ch * 16;
        // epilogue operands for the (dl,n) writer role (L1/L2-resident)
        float xr = xcT[(size_t)d * RT + r + n];
        float zr = zsT[(size_t)d * RT + r + n];
        // staging role (tdd,ti)
        float xv = xcT[(d0 + tdd) * RT + r + ti];
        B_s[tdd][ti] = xdT[(12 + tdd) * RT + r + ti];
        C_s[tdd][ti] = xdT[(28 + tdd) * RT + r + ti];
        if (tid < 192) dtr_s[tid >> 4][ti] = xdT[(tid >> 4) * RT + r + ti];
        __syncthreads();     // staging ready
        float acc = dtb_s[tdd];
#pragma unroll
        for (int rr = 0; rr < DT_RANK; ++rr)
            acc = fmaf(dtr_s[rr][ti], dtw_s[tdd * DT_RANK + rr], acc);
        float dtv = fmaxf(acc, 0.f) + __logf(1.f + __expf(-fabsf(acc)));
        dt_s[tdd][ti] = dtv;
        g_s[tdd][ti]  = dtv * xv;
        __syncthreads();     // dt_s/g_s ready
        float dv[16], gb[16], cv[16];
#pragma unroll
        for (int q = 0; q < 4; ++q) {
            float4 d4 = *(const float4*)&dt_s[dl][q * 4];
            float4 g4 = *(const float4*)&g_s[dl][q * 4];
            float4 b4 = *(const float4*)&B_s[n][q * 4];
            float4 c4 = *(const float4*)&C_s[n][q * 4];
            dv[q * 4 + 0] = d4.x; dv[q * 4 + 1] = d4.y;
            dv[q * 4 + 2] = d4.z; dv[q * 4 + 3] = d4.w;
            gb[q * 4 + 0] = g4.x * b4.x; gb[q * 4 + 1] = g4.y * b4.y;
            gb[q * 4 + 2] = g4.z * b4.z; gb[q * 4 + 3] = g4.w * b4.w;
            cv[q * 4 + 0] = c4.x; cv[q * 4 + 1] = c4.y;
            cv[q * 4 + 2] = c4.z; cv[q * 4 + 3] = c4.w;
        }
        __syncthreads();     // preload done -> next chunk may overwrite LDS
        float eh[16];
#pragma unroll
        for (int i = 0; i < 16; ++i) eh[i] = __expf(dv[i] * a);
        float yacc = 0.f;
#pragma unroll
        for (int i = 0; i < 16; ++i) {
            h = fmaf(eh[i], h, gb[i]);
            float v = row_sum16(h * cv[i]);   // sum over n within the 16-lane row
            yacc = (n == i) ? v : yacc;       // lane n keeps step i==n
        }
        yT[(size_t)d * RT + r + n] = fmaf(xr, Dpd, yacc) * zr;
    }
}

// ---------------------------------------------------------------------------
// K5: out[b, c, l] = sum_d yT[d, row] * out_w[c, d]
// 64x64 tile, 4x4 microtile, 256 threads. grid (128, 3).
// As unpadded [16][64] (staging linear in tid) staged via global_load_lds.
__global__ __launch_bounds__(256) void gemm_out(const float* __restrict__ yT,
                                                const float* __restrict__ out_w,
                                                float* __restrict__ out) {
    __shared__ float As[16][64];  // [k][row], linear
    __shared__ float Bs[16][68];  // [k][c]
    int r0 = blockIdx.x * 64;
    int c0 = blockIdx.y * 64;
    int b = r0 >> 10, l0 = r0 & 1023;
    int tid = threadIdx.x;
    int tx = tid & 15;   // -> row
    int ty = tid >> 4;   // -> c
    float acc[4][4] = {};  // [cc][rc]
    for (int k0 = 0; k0 < DI; k0 += 16) {
        {   // A: yT[k0+k, r0+r..] -> As linear (k*64 + r4 == tid*4)
            gload_lds16(&yT[(k0 + (tid >> 4)) * RT + r0 + (tid & 15) * 4],
                        ((float*)As) + tid * 4);
        }
        {   // B: out_w[c0+c, k0+kc..] -> Bs[kc][c]
            int c = tid >> 2, kc = (tid & 3) * 4;
            float4 v = *(const float4*)&out_w[(c0 + c) * DI + k0 + kc];
            Bs[kc + 0][c] = v.x; Bs[kc + 1][c] = v.y;
            Bs[kc + 2][c] = v.z; Bs[kc + 3][c] = v.w;
        }
        __syncthreads();
#pragma unroll
        for (int k = 0; k < 16; ++k) {
            float4 av = *(const float4*)&As[k][tx * 4];
            float4 bv = *(const float4*)&Bs[k][ty * 4];
            acc[0][0] = fmaf(bv.x, av.x, acc[0][0]);
            acc[0][1] = fmaf(bv.x, av.y, acc[0][1]);
            acc[0][2] = fmaf(bv.x, av.z, acc[0][2]);
            acc[0][3] = fmaf(bv.x, av.w, acc[0][3]);
            acc[1][0] = fmaf(bv.y, av.x, acc[1][0]);
            acc[1][1] = fmaf(bv.y, av.y, acc[1][1]);
            acc[1][2] = fmaf(bv.y, av.z, acc[1][2]);
            acc[1][3] = fmaf(bv.y, av.w, acc[1][3]);
            acc[2][0] = fmaf(bv.z, av.x, acc[2][0]);
            acc[2][1] = fmaf(bv.z, av.y, acc[2][1]);
            acc[2][2] = fmaf(bv.z, av.z, acc[2][2]);
            acc[2][3] = fmaf(bv.z, av.w, acc[2][3]);
            acc[3][0] = fmaf(bv.w, av.x, acc[3][0]);
            acc[3][1] = fmaf(bv.w, av.y, acc[3][1]);
            acc[3][2] = fmaf(bv.w, av.z, acc[3][2]);
            acc[3][3] = fmaf(bv.w, av.w, acc[3][3]);
        }
        __syncthreads();
    }
    float* ob = out + b * CC * LL;
#pragma unroll
    for (int ic = 0; ic < 4; ++ic) {
        float4 o;
        o.x = acc[ic][0]; o.y = acc[ic][1]; o.z = acc[ic][2]; o.w = acc[ic][3];
        *(float4*)&ob[(c0 + ty * 4 + ic) * LL + l0 + tx * 4] = o;
    }
}

// ---------------------------------------------------------------------------
extern "C" void kernel_launch(void* const* d_in, const int* in_sizes, int n_in,
                              void* d_out, int out_size, void* d_ws, size_t ws_size,
                              hipStream_t stream) {
    const float* x         = (const float*)d_in[0];
    const float* proj_w    = (const float*)d_in[1];
    const float* proj_b    = (const float*)d_in[2];
    const float* in_proj_w = (const float*)d_in[3];
    const float* conv_w    = (const float*)d_in[4];
    const float* conv_b    = (const float*)d_in[5];
    const float* xproj_w   = (const float*)d_in[6];
    const float* dtproj_w  = (const float*)d_in[7];
    const float* dtproj_b  = (const float*)d_in[8];
    const float* A_log     = (const float*)d_in[9];
    const float* Dp        = (const float*)d_in[10];
    const float* out_w     = (const float*)d_in[11];
    float* out = (float*)d_out;

    float* ws    = (float*)d_ws;
    float* W2    = ws;                    // 147456
    float* bias2 = W2 + 147456;           // 768
    float* xzT   = bias2 + 768;           // 768*8192 = 6291456 (x raw, z silu'd)
    float* xcT   = xzT + 6291456;         // 3145728
    float* yT    = xcT + 3145728;         // 3145728
    float* xdT   = yT + 3145728;          // 44*8192 = 360448 (0-11 dtr, 12-27 B, 28-43 C)
    float* P     = xdT + 360448;          // 786432
    float* Hf    = P + 786432;            // 786432
    float* zsT   = xzT + DI * RT;         // z half, silu applied by gemm_xz epilogue

    fuse_w_kernel<<<768, 192, 0, stream>>>(in_proj_w, proj_w, proj_b, W2, bias2, xdT);
    gemm_xz<<<dim3(128, 8), 256, 0, stream>>>(x, W2, bias2, xzT);
    xproj_conv_gemm<<<dim3(128, 2), 512, 0, stream>>>(xzT, conv_w, conv_b,
                                                      xproj_w, xcT, xdT);
    scan_part1<<<dim3(16, 24, 8), 256, 0, stream>>>(xdT, xcT, dtproj_w, dtproj_b,
                                                    A_log, P, Hf);
    scan_part2<<<dim3(16, 24, 8), 256, 0, stream>>>(xdT, xcT, zsT, dtproj_w, dtproj_b,
                                                    P, Hf, A_log, Dp, yT);
    gemm_out<<<dim3(128, 3), 256, 0, stream>>>(yT, out_w, out);
}